// Round 11
// baseline (96.120 us; speedup 1.0000x reference)
//
#include <hip/hip_runtime.h>

// Problem constants
#define BATCH 16
#define CIN   64
#define H_    64
#define W_    64
#define IMG   (H_ * W_)      // 4096
#define OCH   128
#define NLEAF 16
#define NGATE 15
#define PH    32
#define PW    32

// d_ws layout: CF = 128 ocs x 15 float4 coeffs (30720 B), then 128 x 16 descs
#define CF_F4_COUNT (OCH * NGATE)       // 1920 float4
#define DESC_I_OFF  (CF_F4_COUNT * 4)   // int offset 7680

// LDS layout (floats). Total 27396 floats = 109,584 B (< 111.6 KB proven
// graph-safe; 140 KB in R9 broke graph replay).
//   [0,1]  guard zeros (desc px-1 underflow target for ch=0,py=0,px=0)
//   XS:    [64 ch][6 rows][66 cols], cols 64,65 zero -> free column halos
//          (col -1 of row r aliases row r-1's zero pad; row stride 66)
//   DS:    leaf descriptors, 128 x 16 ints: XSB + ch*396 + py*66 + px - 1
#define ROWS   6
#define RSTR   66
#define CHSTR  (ROWS * RSTR)            // 396
#define XSB    2
#define DS_F   25348                    // 16B-aligned
#define SMEM_F (DS_F + OCH * NLEAF)     // 27396 floats

typedef float f4v __attribute__((ext_vector_type(4)));

__device__ __constant__ __align__(16) float OP2POLY[16][4] = {
    {0, 0, 0, 0}, {0, 0, 0, 1}, {0, 1, 0, -1}, {0, 1, 0, 0},
    {0, 0, 1, -1}, {0, 0, 1, 0}, {0, 1, 1, -2}, {0, 1, 1, -1},
    {1, -1, -1, 1}, {1, -1, -1, 2}, {1, 0, -1, 0}, {1, 0, -1, 1},
    {1, -1, 0, 0}, {1, -1, 0, 1}, {1, 0, 0, -1}, {1, 0, 0, 0}};

// ---------------------------------------------------------------------------
// Prep: coeffs[oc][g] = OP2POLY[argmax(weights[oc][g][:])] (forward value of
// the straight-through w is exactly the one-hot argmax) as float4 into d_ws,
// plus leaf descriptors desc = XSB + ch*396 + py*66 + px - 1.
// ---------------------------------------------------------------------------
__global__ __launch_bounds__(1024) void prep(
    const float* __restrict__ weights,  // (OC, 15, 16)
    const int* __restrict__ ci,         // (OC, 16)
    const int* __restrict__ px,         // (OC, 16)
    const int* __restrict__ py,         // (OC, 16)
    float* __restrict__ ws)
{
    int t = blockIdx.x * 1024 + threadIdx.x;
    if (t < CF_F4_COUNT) {
        const float4* wp4 = reinterpret_cast<const float4*>(weights + t * 16);
        const float4 a0 = wp4[0], a1 = wp4[1], a2 = wp4[2], a3 = wp4[3];
        const float wv[16] = {a0.x, a0.y, a0.z, a0.w, a1.x, a1.y, a1.z, a1.w,
                              a2.x, a2.y, a2.z, a2.w, a3.x, a3.y, a3.z, a3.w};
        int best = 0;
        float bv = wv[0];
#pragma unroll
        for (int k = 1; k < 16; ++k)
            if (wv[k] > bv) { bv = wv[k]; best = k; }   // first-max (jnp.argmax)
        reinterpret_cast<float4*>(ws)[t] =
            reinterpret_cast<const float4*>(OP2POLY)[best];
    } else if (t < CF_F4_COUNT + OCH * NLEAF) {
        int t2 = t - CF_F4_COUNT;
        ((int*)ws)[DESC_I_OFF + t2] =
            XSB + ci[t2] * CHSTR + py[t2] * RSTR + px[t2] - 1;
    }
}

// ---------------------------------------------------------------------------
// Main. Block = (b, strip of 4 pre-pool rows); 1024 threads = 16 waves;
// XCD swizzle (XCD x -> batches 2x,2x+1). Phase 1: stage x rows r0-1..r0+4
// (64 ch) into stride-66 LDS with zeroed pads (free halos) + descs into LDS.
// Phase 2: wave w -> ocs [8w,8w+8); lane = column. Per oc: descs via LDS
// (lgkmcnt, in-order with leaf reads); coefficients via per-lane
// global_load_dwordx4 from d_ws (oc is divergent -> vector load; 64 lanes
// broadcast one L1 line; vmcnt counter, INDEPENDENT of lgkmcnt -> no
// full-drain waits mixing SMEM into the LDS pipeline, which was the R5-R10
// stall). 4 rows per leaf as f4 (2x ds_read2_b32); 15-gate tree; 2x2
// noisy-or pool; one all-lane store.
// ---------------------------------------------------------------------------
__global__ __launch_bounds__(1024, 4) void logic_tree_main(
    const float* __restrict__ x,        // (B, Cin, 64, 64)
    const float* __restrict__ ws,
    float* __restrict__ out)            // (B, OC, 32, 32)
{
    __shared__ float smem[SMEM_F];
    int* smem_i = (int*)smem;

    const int blk = blockIdx.x;
    const int xcd = blk & 7;
    const int j   = blk >> 3;
    const int b   = (xcd << 1) | (j >> 4);
    const int strip = j & 15;
    const int r0  = strip << 2;
    const int tid = threadIdx.x;

    // ---- stage x interior (float2 loads) ----
    const float2* xb2 =
        reinterpret_cast<const float2*>(x + (size_t)b * (CIN * IMG));
#pragma unroll
    for (int i = 0; i < 12; ++i) {
        int f   = tid + i * 1024;        // < 12288 float2s
        int ch  = f / 192;               // 192 float2 per channel (6 rows x 32)
        int rem = f - ch * 192;
        int row = rem >> 5;
        int c2  = rem & 31;
        int gr  = r0 - 1 + row;
        float2 val = make_float2(0.f, 0.f);
        if ((unsigned)gr < (unsigned)H_)
            val = xb2[((ch << 6) | gr) * 32 + c2];
        *reinterpret_cast<float2*>(&smem[XSB + ch * CHSTR + row * RSTR + c2 * 2]) = val;
    }
    // ---- zero pads: cols 64,65 of each (ch,row) + 2 guard floats ----
    if (tid < 770) {
        int idx = (tid < 768) ? (XSB + (tid >> 1) * RSTR + 64 + (tid & 1))
                              : (tid - 768);
        smem[idx] = 0.0f;
    }
    // ---- stage leaf descriptors (coalesced) ----
#pragma unroll
    for (int i = 0; i < 2; ++i)
        smem_i[DS_F + tid + i * 1024] =
            ((const int*)ws)[DESC_I_OFF + tid + i * 1024];
    __syncthreads();

    const int wave = tid >> 6;
    const int lane = tid & 63;
    const size_t obase0 =
        (((size_t)b * OCH) * PH + (strip << 1) + (lane & 1)) * PW + (lane >> 1);

#pragma unroll 1
    for (int q = 0; q < 8; ++q) {
        const int oc = wave * 8 + q;     // divergent -> coeff loads stay vector

        // leaf descriptors (contiguous -> int4 LDS loads), base = desc + lane
        int base[NLEAF];
        const int4* D4 = reinterpret_cast<const int4*>(smem_i + DS_F + oc * NLEAF);
#pragma unroll
        for (int m = 0; m < 4; ++m) {
            const int4 d = D4[m];
            base[4 * m + 0] = d.x + lane;
            base[4 * m + 1] = d.y + lane;
            base[4 * m + 2] = d.z + lane;
            base[4 * m + 3] = d.w + lane;
        }

        // rows r0..r0+3 per leaf as one f4 (two ds_read2_b32: 0/66, 132/198)
        f4v v[NLEAF];
#pragma unroll
        for (int n = 0; n < NLEAF; ++n) {
            v[n].x = smem[base[n]];
            v[n].y = smem[base[n] + RSTR];
            v[n].z = smem[base[n] + 2 * RSTR];
            v[n].w = smem[base[n] + 3 * RSTR];
        }

        // 15-gate polynomial tree, 4 rows wide; coeffs via vector global
        // loads (vmcnt) -- L1-broadcast, no lgkmcnt interference
        const float4* C4 = reinterpret_cast<const float4*>(ws) + oc * NGATE;
        int go = 0;
#pragma unroll
        for (int lev = 8; lev >= 1; lev >>= 1) {
#pragma unroll
            for (int t = 0; t < lev; ++t) {
                const float4 cc = C4[go + t];
                f4v a  = v[2 * t];
                f4v bb = v[2 * t + 1];
                v[t] = cc.x + cc.y * a + cc.z * bb + cc.w * (a * bb);
            }
            go += lev;
        }

        // 2x2 noisy-or pool; even lanes -> pooled row 2*strip, odd -> +1
        float p0 = (1.0f - v[0].x) * (1.0f - v[0].y);
        float p1 = (1.0f - v[0].z) * (1.0f - v[0].w);
        float q0 = p0 * __shfl_xor(p0, 1, 64);
        float q1 = p1 * __shfl_xor(p1, 1, 64);
        float val = (lane & 1) ? (1.0f - q1) : (1.0f - q0);
        out[obase0 + (size_t)oc * (PH * PW)] = val;
    }
}

extern "C" void kernel_launch(void* const* d_in, const int* in_sizes, int n_in,
                              void* d_out, int out_size, void* d_ws, size_t ws_size,
                              hipStream_t stream) {
    const float* x       = (const float*)d_in[0];
    const float* weights = (const float*)d_in[1];
    const int*   ci      = (const int*)d_in[2];
    const int*   px      = (const int*)d_in[3];
    const int*   py      = (const int*)d_in[4];
    float* out = (float*)d_out;
    float* ws  = (float*)d_ws;   // needs ~39 KB

    prep<<<4, 1024, 0, stream>>>(weights, ci, px, py, ws);
    logic_tree_main<<<BATCH * 16, 1024, 0, stream>>>(x, ws, out);
}